// Round 10
// baseline (151.771 us; speedup 1.0000x reference)
//
#include <hip/hip_runtime.h>
#include <hip/hip_bf16.h>

#define N 1024
#define D 64
#define H1 128
#define H2 64
#define FLAG_THRESH 0.015f
#define FLAG_CAP 1024   // mean flags/block ~15; Binomial(2048,0.0075) never nears 1024
#define H1PAD 136       // f16 LDS row stride: 272 B = 17*16B (b128-aligned, 2-way banks only)

typedef _Float16 half8 __attribute__((ext_vector_type(8)));
typedef float float4v __attribute__((ext_vector_type(4)));

// ---------------------------------------------------------------------------
// K1: pre-activations, exact f64 + f16 copies.
//   A = X @ W1[:64,:] + b1   (1024 x 128)
//   B = X @ W1[64:,:]        (1024 x 128)
// ---------------------------------------------------------------------------
__global__ __launch_bounds__(128) void precompute_kernel(
    const float* __restrict__ X, const float* __restrict__ W1,
    const float* __restrict__ b1,
    double* __restrict__ A64, double* __restrict__ B64,
    _Float16* __restrict__ A16, _Float16* __restrict__ B16)
{
    int i = blockIdx.x;
    int k = threadIdx.x;
    double a = (double)b1[k];
    double b = 0.0;
    for (int c = 0; c < D; ++c) {
        double x = (double)X[i * D + c];              // wave-uniform
        a += x * (double)W1[c * H1 + k];
        b += x * (double)W1[(D + c) * H1 + k];
    }
    A64[i * H1 + k] = a;
    B64[i * H1 + k] = b;
    A16[i * H1 + k] = (_Float16)(float)a;
    B16[i * H1 + k] = (_Float16)(float)b;
}

// ---------------------------------------------------------------------------
// K2: FUSED symmetric pair-MLP + gumbel epilogue + f64 repair.
// Grid = 528 upper-triangular 32x32 tile-pairs (ti <= tj). Each block:
//   1. stages A16/B16 rows for I and J, W2 (f16, transposed)
//   2. MFMA (operand-swapped: A=W2, B=h) computes S_ij = d(I,J), S_ji = d(J,I)
//      wave = (dir, col-half); hb loaded once per wave, reused over 32 rows
//   3. symmetrize via LDS: Dlogit = 0.5*(S_ij[i][j] + S_ji[j][i])
//   4. gumbel (fast __logf) + sign -> out[I,J] and out[J,I]; |Dv|<thresh -> flag
//   5. per-wave exact f64 repair of this block's flags (h1s overlays S buffers)
// ---------------------------------------------------------------------------
__global__ __launch_bounds__(256, 2) void fused_pair_kernel(
    const _Float16* __restrict__ A16, const _Float16* __restrict__ B16,
    const double* __restrict__ A64, const double* __restrict__ B64,
    const float* __restrict__ W2, const float* __restrict__ b2,
    const float* __restrict__ W3, const float* __restrict__ b3,
    const float* __restrict__ u, float* __restrict__ out)
{
    __shared__ _Float16 Ar[64 * H1PAD];     // rows 0-31: A16[I], 32-63: A16[J]
    __shared__ _Float16 Br[64 * H1PAD];     // rows 0-31: B16[I], 32-63: B16[J]
    __shared__ _Float16 W2t[64 * H1PAD];    // W2t[n][k] = W2[k][n]
    __shared__ __align__(16) unsigned char overlay[2 * 32 * 33 * 4];  // 8448 B
    __shared__ unsigned int lflags[FLAG_CAP];
    __shared__ unsigned int lcnt;

    float (*Sij)[33] = (float(*)[33])overlay;                    // d(I_i, J_j)
    float (*Sji)[33] = (float(*)[33])(overlay + 32 * 33 * 4);    // d(J_j, I_i)

    int tid = threadIdx.x;
    // triangular decode (uniform scalar loop, <=32 iters)
    int t = blockIdx.x, ti = 0;
    while (t >= 32 - ti) { t -= 32 - ti; ++ti; }
    int tj = ti + t;
    int I0 = ti << 5, J0 = tj << 5;
    if (tid == 0) lcnt = 0;

    // ---- stage A/B rows (64 rows x 128 f16 each): 8 f16 per thread per iter
    #pragma unroll
    for (int it = 0; it < 4; ++it) {
        int v = tid + it * 256;          // 0..1023 = 64 rows x 16 chunks
        int row = v >> 4;
        int col = (v & 15) << 3;
        int gr = (row < 32) ? (I0 + row) : (J0 + row - 32);
        *(half8*)&Ar[row * H1PAD + col] = *(const half8*)&A16[(size_t)gr * H1 + col];
        *(half8*)&Br[row * H1PAD + col] = *(const half8*)&B16[(size_t)gr * H1 + col];
    }
    // ---- stage W2 transposed to f16
    #pragma unroll
    for (int r = 0; r < 32; ++r) {
        int idx = tid + r * 256;         // 0..8191
        int k = idx >> 6, n = idx & 63;
        W2t[n * H1PAD + k] = (_Float16)W2[idx];
    }
    __syncthreads();

    int lane = tid & 63;
    int wave = tid >> 6;
    int quad = lane >> 4;                // 0..3
    int m = lane & 15;

    // ---- A-frags: W2 in registers. afrag[ks][nt]: A[m][k] = W2[k][m+16nt]
    half8 afrag[4][4];
    #pragma unroll
    for (int ks = 0; ks < 4; ++ks)
        #pragma unroll
        for (int nt = 0; nt < 4; ++nt)
            afrag[ks][nt] = *(const half8*)&W2t[(m + 16 * nt) * H1PAD + quad * 8 + 32 * ks];

    // ---- per-lane layer-3 constants: o = quad*4+reg+16*nt
    float b2x[4][4], w3x[4][4];
    #pragma unroll
    for (int nt = 0; nt < 4; ++nt)
        #pragma unroll
        for (int reg = 0; reg < 4; ++reg) {
            int o = (quad << 2) + reg + (nt << 4);
            b2x[nt][reg] = b2[o];
            w3x[nt][reg] = W3[o * 2 + 1] - W3[o * 2 + 0];
        }

    const half8 zero8 = {0, 0, 0, 0, 0, 0, 0, 0};

    // wave -> (direction, col-half). dir 0: S_ij (A-rows I, B-cols J);
    //                                dir 1: S_ji (A-rows J, B-cols I).
    int dir = wave >> 1;
    int jh = wave & 1;
    int abase = dir ? 32 : 0;
    int bbase = dir ? 0 : 32;
    float (*Sout)[33] = dir ? Sji : Sij;

    half8 hb[4];                         // this lane's col row: loaded ONCE
    #pragma unroll
    for (int ks = 0; ks < 4; ++ks)
        hb[ks] = *(const half8*)&Br[(bbase + jh * 16 + m) * H1PAD + quad * 8 + 32 * ks];

    #pragma unroll 1
    for (int ii = 0; ii < 32; ++ii) {
        float4v acc[4];
        #pragma unroll
        for (int nt = 0; nt < 4; ++nt)
            acc[nt] = (float4v){b2x[nt][0], b2x[nt][1], b2x[nt][2], b2x[nt][3]};

        #pragma unroll
        for (int ks = 0; ks < 4; ++ks) {
            half8 ha = *(const half8*)&Ar[(abase + ii) * H1PAD + quad * 8 + 32 * ks];
            half8 h = __builtin_elementwise_max(ha + hb[ks], zero8);
            #pragma unroll
            for (int nt = 0; nt < 4; ++nt)
                acc[nt] = __builtin_amdgcn_mfma_f32_16x16x32_f16(afrag[ks][nt], h, acc[nt], 0, 0, 0);
        }
        float s = 0.f;
        #pragma unroll
        for (int nt = 0; nt < 4; ++nt)
            #pragma unroll
            for (int reg = 0; reg < 4; ++reg)
                s = fmaf(fmaxf(acc[nt][reg], 0.f), w3x[nt][reg], s);
        s += __shfl_xor(s, 16, 64);
        s += __shfl_xor(s, 32, 64);
        if (quad == 0) Sout[ii][jh * 16 + m] = s;
    }
    __syncthreads();

    // ---------------- epilogue passes (fast __logf gumbel) ----------------
    float b3d = b3[1] - b3[0];
    {   // pass 1: [I,J] block
        int i = tid >> 3, j0 = (tid & 7) << 2;
        int ij0 = (I0 + i) * N + (J0 + j0);
        float4 u01 = *(const float4*)&u[((size_t)ij0) * 2];
        float4 u23 = *(const float4*)&u[((size_t)ij0) * 2 + 4];
        float uu[8] = {u01.x, u01.y, u01.z, u01.w, u23.x, u23.y, u23.z, u23.w};
        float4 res; float* resp = &res.x;
        #pragma unroll
        for (int q = 0; q < 4; ++q) {
            int j = j0 + q;
            float l0 = -__logf(uu[2 * q] + 1e-10f) + 1e-10f;
            float l1 = -__logf(uu[2 * q + 1] + 1e-10f) + 1e-10f;
            float Dv = 0.5f * (Sij[i][j] + Sji[j][i]) + b3d + __logf(l0 / l1);
            resp[q] = Dv > 0.f ? 1.f : 0.f;
            if (fabsf(Dv) < FLAG_THRESH) {
                unsigned int idx = atomicAdd(&lcnt, 1u);
                if (idx < FLAG_CAP) lflags[idx] = (unsigned int)(ij0 + q);
            }
        }
        *(float4*)&out[ij0] = res;
    }
    if (ti != tj) {   // pass 2: [J,I] block (own gumbel draws)
        int j = tid >> 3, i0 = (tid & 7) << 2;
        int ij0 = (J0 + j) * N + (I0 + i0);
        float4 u01 = *(const float4*)&u[((size_t)ij0) * 2];
        float4 u23 = *(const float4*)&u[((size_t)ij0) * 2 + 4];
        float uu[8] = {u01.x, u01.y, u01.z, u01.w, u23.x, u23.y, u23.z, u23.w};
        float4 res; float* resp = &res.x;
        #pragma unroll
        for (int q = 0; q < 4; ++q) {
            int i = i0 + q;
            float l0 = -__logf(uu[2 * q] + 1e-10f) + 1e-10f;
            float l1 = -__logf(uu[2 * q + 1] + 1e-10f) + 1e-10f;
            float Dv = 0.5f * (Sji[j][i] + Sij[i][j]) + b3d + __logf(l0 / l1);
            resp[q] = Dv > 0.f ? 1.f : 0.f;
            if (fabsf(Dv) < FLAG_THRESH) {
                unsigned int idx = atomicAdd(&lcnt, 1u);
                if (idx < FLAG_CAP) lflags[idx] = (unsigned int)(ij0 + q);
            }
        }
        *(float4*)&out[ij0] = res;
    }

    // publish lflags; drain main out-stores (vmcnt(0) before s_barrier);
    // frees overlay for h1s reuse.
    __syncthreads();

    // ---------------- repair phase (exact f64, per-wave) ----------------
    unsigned int nl = lcnt;
    if (nl > FLAG_CAP) nl = FLAG_CAP;
    double (*h1s)[2][H1] = (double(*)[2][H1])overlay;   // [4][2][128] = 8192 B
    double w3dd = (double)W3[lane * 2 + 1] - (double)W3[lane * 2 + 0];
    double b2d = (double)b2[lane];

    for (unsigned int f = wave; f < nl; f += 4) {
        int ij = (int)lflags[f];
        int i = ij >> 10, j = ij & (N - 1);
        double uvd = 0.0;
        if (lane < 2) uvd = (double)u[(((size_t)ij) << 1) + lane];
        {   // lane = k (two k's per lane), coalesced f64 loads
            int k0 = lane, k1 = lane + 64;
            double ai0 = A64[(size_t)i * H1 + k0], ai1 = A64[(size_t)i * H1 + k1];
            double aj0 = A64[(size_t)j * H1 + k0], aj1 = A64[(size_t)j * H1 + k1];
            double bi0 = B64[(size_t)i * H1 + k0], bi1 = B64[(size_t)i * H1 + k1];
            double bj0 = B64[(size_t)j * H1 + k0], bj1 = B64[(size_t)j * H1 + k1];
            double v;
            v = ai0 + bj0; h1s[wave][0][k0] = v > 0.0 ? v : 0.0;
            v = ai1 + bj1; h1s[wave][0][k1] = v > 0.0 ? v : 0.0;
            v = aj0 + bi0; h1s[wave][1][k0] = v > 0.0 ? v : 0.0;
            v = aj1 + bi1; h1s[wave][1][k1] = v > 0.0 ? v : 0.0;
        }
        asm volatile("s_waitcnt lgkmcnt(0)" ::: "memory");
        __builtin_amdgcn_wave_barrier();

        // 8 independent chains: latency-hides the f64 FMA dep chain
        const double* __restrict__ hap = h1s[wave][0];
        const double* __restrict__ hbp = h1s[wave][1];
        double sa0 = 0.0, sa1 = 0.0, sa2 = 0.0, sa3 = 0.0;
        double sb0 = 0.0, sb1 = 0.0, sb2 = 0.0, sb3 = 0.0;
        #pragma unroll 2
        for (int k = 0; k < H1; k += 4) {
            double w0 = (double)W2[(k + 0) * H2 + lane];
            double w1 = (double)W2[(k + 1) * H2 + lane];
            double w2v = (double)W2[(k + 2) * H2 + lane];
            double w3v = (double)W2[(k + 3) * H2 + lane];
            sa0 += hap[k + 0] * w0;  sa1 += hap[k + 1] * w1;
            sa2 += hap[k + 2] * w2v; sa3 += hap[k + 3] * w3v;
            sb0 += hbp[k + 0] * w0;  sb1 += hbp[k + 1] * w1;
            sb2 += hbp[k + 2] * w2v; sb3 += hbp[k + 3] * w3v;
        }
        double sa = ((sa0 + sa1) + (sa2 + sa3)) + b2d;
        double sb = ((sb0 + sb1) + (sb2 + sb3)) + b2d;
        if (sa < 0.0) sa = 0.0;
        if (sb < 0.0) sb = 0.0;
        double da = sa * w3dd;
        double db = sb * w3dd;
        #pragma unroll
        for (int off = 32; off > 0; off >>= 1) {
            da += __shfl_down(da, off, 64);
            db += __shfl_down(db, off, 64);
        }
        double g = 0.0;
        if (lane < 2) g = -log(-log(uvd + 1e-10) + 1e-10);   // lanes 0,1 in parallel
        double g0 = __shfl(g, 0, 64);
        double g1 = __shfl(g, 1, 64);
        if (lane == 0) {
            double b3dd = (double)b3[1] - (double)b3[0];
            double Dv = 0.5 * (da + db) + b3dd + (g1 - g0);
            out[ij] = Dv > 0.0 ? 1.f : 0.f;
        }
        __builtin_amdgcn_wave_barrier();   // DS in-order per wave; stop reordering
    }
}

// ---------------------------------------------------------------------------
extern "C" void kernel_launch(void* const* d_in, const int* in_sizes, int n_in,
                              void* d_out, int out_size, void* d_ws, size_t ws_size,
                              hipStream_t stream) {
    const float* X  = (const float*)d_in[0];
    const float* W1 = (const float*)d_in[1];
    const float* b1 = (const float*)d_in[2];
    const float* W2 = (const float*)d_in[3];
    const float* b2 = (const float*)d_in[4];
    const float* W3 = (const float*)d_in[5];
    const float* b3 = (const float*)d_in[6];
    const float* u  = (const float*)d_in[7];
    float* out = (float*)d_out;

    // workspace layout (doubles first for alignment)
    double* A64 = (double*)d_ws;                         // 1 MB
    double* B64 = A64 + (size_t)N * H1;                  // 1 MB
    _Float16* A16 = (_Float16*)(B64 + (size_t)N * H1);   // 256 KB
    _Float16* B16 = A16 + (size_t)N * H1;                // 256 KB

    precompute_kernel<<<N, 128, 0, stream>>>(X, W1, b1, A64, B64, A16, B16);
    fused_pair_kernel<<<528, 256, 0, stream>>>(A16, B16, A64, B64,
                                               W2, b2, W3, b3, u, out);
}